// Round 1
// baseline (1829.602 us; speedup 1.0000x reference)
//
#include <hip/hip_runtime.h>

// ---------------------------------------------------------------------------
// 2-layer GraphConv (DGL norm='both') + per-graph mean readout.
// Pipeline:
//   0. memset scratch (degrees, agg buffers, graph sums)
//   1. k_degree:   unweighted in/out degrees via fp32 atomics
//   2. k_norm:     deg -> deg^-0.5 (clipped at 1)
//   3. k_gemm<128>: t1 = x @ W1                      (f32, VALU)
//   4. k_scatter128: agg1[dst] += t1[src]*nsrc[src]*ew   (atomics)
//   5. k_elem:     h1 = leaky(agg1 * ndst)  in place
//   6. k_gemm<64>: t2 = h1 @ W2   (t2 reuses t1 region)
//   7. k_scatter64: agg2[dst] += t2[src]*nsrc[src]*ew
//   8. k_readout:  h2 = leaky(agg2*ndst); gsum[graph] += h2; gcnt[graph]++
//   9. k_finalize: out = gsum / max(gcnt,1)
// ---------------------------------------------------------------------------

__device__ __forceinline__ float leaky(float v) { return v > 0.f ? v : 0.01f * v; }

__global__ __launch_bounds__(256) void k_degree(const int* __restrict__ src,
                                                const int* __restrict__ dst,
                                                float* __restrict__ dout,
                                                float* __restrict__ din, int E) {
    int e = blockIdx.x * 256 + threadIdx.x;
    if (e < E) {
        unsafeAtomicAdd(&dout[src[e]], 1.f);
        unsafeAtomicAdd(&din[dst[e]], 1.f);
    }
}

__global__ __launch_bounds__(256) void k_norm(float* __restrict__ a,
                                              float* __restrict__ b, int N) {
    int i = blockIdx.x * 256 + threadIdx.x;
    if (i < N) {
        a[i] = rsqrtf(fmaxf(a[i], 1.f));
        b[i] = rsqrtf(fmaxf(b[i], 1.f));
    }
}

// C[N][BN] = A[N][K] @ W[K][BN].  BM=64 rows/block, BK=32 K-chunk,
// 256 threads as 16x16; each thread computes a 4 x TN register tile.
template <int BN, int TN>
__global__ __launch_bounds__(256) void k_gemm(const float* __restrict__ A,
                                              const float* __restrict__ W,
                                              float* __restrict__ C, int N, int K) {
    constexpr int BM = 64, BK = 32;
    __shared__ float Xs[BM][BK + 1];   // +1 pad: conflict-free column reads
    __shared__ float Ws[BK][BN];       // float4 reads are 2-way -> free

    const int tid = threadIdx.x;
    const int r0 = blockIdx.x * BM;
    const int ty = tid >> 4;           // 0..15 -> row group of 4
    const int tx = tid & 15;           // 0..15 -> col group of TN

    float acc[4][TN];
#pragma unroll
    for (int i = 0; i < 4; ++i)
#pragma unroll
        for (int j = 0; j < TN; ++j) acc[i][j] = 0.f;

    const int lrow = tid >> 2;         // 64 rows, 4 threads/row
    const int lc = (tid & 3) * 4;      // 2 float4 per thread -> 32 floats/row
    const int kr = tid >> 3;           // 32 W-rows, 8 threads/row

    for (int kc = 0; kc < K; kc += BK) {
        // stage X tile [64][32]
        const int gr = r0 + lrow;
        if (gr < N) {
            *(float4*)&Xs[lrow][lc]      = *(const float4*)&A[(size_t)gr * K + kc + lc];
            *(float4*)&Xs[lrow][lc + 16] = *(const float4*)&A[(size_t)gr * K + kc + lc + 16];
        } else {
            *(float4*)&Xs[lrow][lc]      = float4{0.f, 0.f, 0.f, 0.f};
            *(float4*)&Xs[lrow][lc + 16] = float4{0.f, 0.f, 0.f, 0.f};
        }
        // stage W tile [32][BN]: 8 threads/row, BN/32 float4 each
#pragma unroll
        for (int j = 0; j < BN / 32; ++j) {
            const int c4 = (tid & 7) + j * 8;  // float4 index within row
            *(float4*)&Ws[kr][c4 * 4] =
                *(const float4*)&W[(size_t)(kc + kr) * BN + c4 * 4];
        }
        __syncthreads();

#pragma unroll
        for (int k = 0; k < BK; ++k) {
            float xv[4];
#pragma unroll
            for (int i = 0; i < 4; ++i) xv[i] = Xs[ty * 4 + i][k];
            float wv[TN];
#pragma unroll
            for (int j4 = 0; j4 < TN / 4; ++j4) {
                const float4 w4 = *(const float4*)&Ws[k][tx * TN + j4 * 4];
                wv[j4 * 4 + 0] = w4.x; wv[j4 * 4 + 1] = w4.y;
                wv[j4 * 4 + 2] = w4.z; wv[j4 * 4 + 3] = w4.w;
            }
#pragma unroll
            for (int i = 0; i < 4; ++i)
#pragma unroll
                for (int j = 0; j < TN; ++j) acc[i][j] = fmaf(xv[i], wv[j], acc[i][j]);
        }
        __syncthreads();
    }

#pragma unroll
    for (int i = 0; i < 4; ++i) {
        const int r = r0 + ty * 4 + i;
        if (r < N) {
#pragma unroll
            for (int j4 = 0; j4 < TN / 4; ++j4) {
                float4 o{acc[i][j4 * 4 + 0], acc[i][j4 * 4 + 1],
                         acc[i][j4 * 4 + 2], acc[i][j4 * 4 + 3]};
                *(float4*)&C[(size_t)r * BN + tx * TN + j4 * 4] = o;
            }
        }
    }
}

// one 32-lane group per edge, F=128 (float4/lane)
__global__ __launch_bounds__(256) void k_scatter128(const int* __restrict__ src,
                                                    const int* __restrict__ dst,
                                                    const float* __restrict__ ew,
                                                    const float* __restrict__ nsrc,
                                                    const float* __restrict__ h,
                                                    float* __restrict__ agg, int E) {
    const int e = blockIdx.x * 8 + (threadIdx.x >> 5);
    if (e >= E) return;
    const int lane = threadIdx.x & 31;
    const int s = src[e], d = dst[e];
    const float sc = nsrc[s] * ew[e];
    const float4 v = *(const float4*)&h[(size_t)s * 128 + lane * 4];
    float* out = &agg[(size_t)d * 128 + lane * 4];
    unsafeAtomicAdd(out + 0, v.x * sc);
    unsafeAtomicAdd(out + 1, v.y * sc);
    unsafeAtomicAdd(out + 2, v.z * sc);
    unsafeAtomicAdd(out + 3, v.w * sc);
}

// one 16-lane group per edge, F=64
__global__ __launch_bounds__(256) void k_scatter64(const int* __restrict__ src,
                                                   const int* __restrict__ dst,
                                                   const float* __restrict__ ew,
                                                   const float* __restrict__ nsrc,
                                                   const float* __restrict__ h,
                                                   float* __restrict__ agg, int E) {
    const int e = blockIdx.x * 16 + (threadIdx.x >> 4);
    if (e >= E) return;
    const int lane = threadIdx.x & 15;
    const int s = src[e], d = dst[e];
    const float sc = nsrc[s] * ew[e];
    const float4 v = *(const float4*)&h[(size_t)s * 64 + lane * 4];
    float* out = &agg[(size_t)d * 64 + lane * 4];
    unsafeAtomicAdd(out + 0, v.x * sc);
    unsafeAtomicAdd(out + 1, v.y * sc);
    unsafeAtomicAdd(out + 2, v.z * sc);
    unsafeAtomicAdd(out + 3, v.w * sc);
}

// h1 = leaky(agg1 * ndst), in place, F=128
__global__ __launch_bounds__(256) void k_elem(float* __restrict__ a,
                                              const float* __restrict__ ndst, int N) {
    const int idx = blockIdx.x * 256 + threadIdx.x;  // one float4 per thread
    if (idx >= N * 32) return;
    const int node = idx >> 5;
    const float nd = ndst[node];
    float4 v = *(float4*)&a[(size_t)idx * 4];
    v.x = leaky(v.x * nd); v.y = leaky(v.y * nd);
    v.z = leaky(v.z * nd); v.w = leaky(v.w * nd);
    *(float4*)&a[(size_t)idx * 4] = v;
}

// per-node: h2 = leaky(agg2*ndst); atomically accumulate into graph sums
__global__ __launch_bounds__(256) void k_readout(const float* __restrict__ agg2,
                                                 const float* __restrict__ ndst,
                                                 const int* __restrict__ gid,
                                                 float* __restrict__ gsum,
                                                 float* __restrict__ gcnt, int N) {
    const int idx = blockIdx.x * 256 + threadIdx.x;
    const int node = idx >> 4;
    if (node >= N) return;
    const int lane = idx & 15;
    const int g = gid[node];
    const float nd = ndst[node];
    const float4 v = *(const float4*)&agg2[(size_t)node * 64 + lane * 4];
    float* out = &gsum[(size_t)g * 64 + lane * 4];
    unsafeAtomicAdd(out + 0, leaky(v.x * nd));
    unsafeAtomicAdd(out + 1, leaky(v.y * nd));
    unsafeAtomicAdd(out + 2, leaky(v.z * nd));
    unsafeAtomicAdd(out + 3, leaky(v.w * nd));
    if (lane == 0) unsafeAtomicAdd(&gcnt[g], 1.f);
}

__global__ __launch_bounds__(256) void k_finalize(const float* __restrict__ gsum,
                                                  const float* __restrict__ gcnt,
                                                  float* __restrict__ out, int total) {
    const int i = blockIdx.x * 256 + threadIdx.x;
    if (i < total) out[i] = gsum[i] / fmaxf(gcnt[i >> 6], 1.f);
}

extern "C" void kernel_launch(void* const* d_in, const int* in_sizes, int n_in,
                              void* d_out, int out_size, void* d_ws, size_t ws_size,
                              hipStream_t stream) {
    const float* x   = (const float*)d_in[0];
    const float* ew  = (const float*)d_in[1];
    const float* W1  = (const float*)d_in[2];
    const float* W2  = (const float*)d_in[3];
    const int*   src = (const int*)d_in[4];
    const int*   dst = (const int*)d_in[5];
    const int*   gid = (const int*)d_in[6];

    const int N  = in_sizes[6];      // 50000 nodes
    const int E  = in_sizes[4];      // 600000 edges
    const int NG = out_size / 64;    // 128 graphs

    // workspace layout (floats); zeroed prefix first, t1 un-zeroed at the end
    float* ws      = (float*)d_ws;
    float* deg_out = ws;                              // N
    float* deg_in  = deg_out + N;                     // N
    float* agg2    = deg_in + N;                      // N*64
    float* gsum    = agg2 + (size_t)N * 64;           // NG*64
    float* gcnt    = gsum + (size_t)NG * 64;          // NG
    float* agg1    = gcnt + NG;                       // N*128  (zeroed, -> h1)
    float* t1      = agg1 + (size_t)N * 128;          // N*128  (t1, then t2)

    const size_t zero_bytes = (size_t)(t1 - ws) * sizeof(float);
    hipMemsetAsync(d_ws, 0, zero_bytes, stream);

    k_degree<<<(E + 255) / 256, 256, 0, stream>>>(src, dst, deg_out, deg_in, E);
    k_norm<<<(N + 255) / 256, 256, 0, stream>>>(deg_out, deg_in, N);

    k_gemm<128, 8><<<(N + 63) / 64, 256, 0, stream>>>(x, W1, t1, N, 128);
    k_scatter128<<<(E + 7) / 8, 256, 0, stream>>>(src, dst, ew, deg_out, t1, agg1, E);
    k_elem<<<((size_t)N * 32 + 255) / 256, 256, 0, stream>>>(agg1, deg_in, N);

    k_gemm<64, 4><<<(N + 63) / 64, 256, 0, stream>>>(agg1, W2, t1, N, 128);
    k_scatter64<<<(E + 15) / 16, 256, 0, stream>>>(src, dst, ew, deg_out, t1, agg2, E);

    k_readout<<<((size_t)N * 16 + 255) / 256, 256, 0, stream>>>(agg2, deg_in, gid,
                                                                gsum, gcnt, N);
    k_finalize<<<(NG * 64 + 255) / 256, 256, 0, stream>>>(gsum, gcnt, (float*)d_out,
                                                          NG * 64);
}

// Round 4
// 448.786 us; speedup vs baseline: 4.0768x; 4.0768x over previous
//
#include <hip/hip_runtime.h>

// ---------------------------------------------------------------------------
// 2-layer GraphConv (DGL norm='both') + per-graph mean readout.
// R1-R3: replace scatter-atomics (76.8M+38.4M fp32 memory-side atomics, 1.2GB
// write amplification, 990us measured in R0) with device-built CSR-by-dst +
// pull aggregation.
// Pipeline:
//   0. memset: cnt_in, cnt_out, gsum, gcnt (small)
//   1. k_count:  int in/out degrees
//   2. k_scan1/2/3: exclusive scan of cnt_in -> row_off, cursor; fused norms
//   3. k_fill:   CSR slots: sidx[pos]=src, wgt[pos]=norm_out[src]*ew
//   4. k_gemm<128>: t1 = x @ W1
//   5. k_agg<128>:  h1[n] = leaky(norm_in[n] * sum_j wgt*t1[sidx])   (pull)
//   6. k_gemm<64>:  t2 = h1 @ W2
//   7. k_agg_readout: h2 per node -> atomic into gsum/gcnt (8K addresses)
//   8. k_finalize
// ---------------------------------------------------------------------------

#define LB256 __launch_bounds__(256)

__device__ __forceinline__ float leaky(float v) { return v > 0.f ? v : 0.01f * v; }

__global__ LB256 void k_count(const int* __restrict__ src, const int* __restrict__ dst,
                              int* __restrict__ cin, int* __restrict__ cout_, int E) {
    int e = blockIdx.x * 256 + threadIdx.x;
    if (e < E) {
        atomicAdd(&cout_[src[e]], 1);
        atomicAdd(&cin[dst[e]], 1);
    }
}

// inclusive block scan helper: returns inclusive scan of v across 256 threads
__device__ __forceinline__ int block_scan_incl(int v, int t) {
    const int lane = t & 63, w = t >> 6;
#pragma unroll
    for (int off = 1; off < 64; off <<= 1) {
        int n = __shfl_up(v, off);
        if (lane >= off) v += n;
    }
    __shared__ int wsum[4];
    if (lane == 63) wsum[w] = v;
    __syncthreads();
    int base = 0;
#pragma unroll
    for (int k = 0; k < 4; ++k)
        if (k < w) base += wsum[k];
    return v + base;
}

__global__ LB256 void k_scan1(const int* __restrict__ cnt, int* __restrict__ excl,
                              int* __restrict__ bsum, int N) {
    const int t = threadIdx.x, i = blockIdx.x * 256 + t;
    const int orig = (i < N) ? cnt[i] : 0;
    const int incl = block_scan_incl(orig, t);
    if (i < N) excl[i] = incl - orig;
    if (t == 255) bsum[blockIdx.x] = incl;
}

__global__ LB256 void k_scan2(const int* __restrict__ bsum, int* __restrict__ boff, int NB) {
    const int t = threadIdx.x;
    const int orig = (t < NB) ? bsum[t] : 0;
    const int incl = block_scan_incl(orig, t);
    if (t < NB) boff[t] = incl - orig;
}

__global__ LB256 void k_scan3(const int* __restrict__ excl, const int* __restrict__ boff,
                              const int* __restrict__ cin, const int* __restrict__ cout_,
                              int* __restrict__ row_off, int* __restrict__ cursor,
                              float* __restrict__ nin, float* __restrict__ nout, int N) {
    const int i = blockIdx.x * 256 + threadIdx.x;
    if (i < N) {
        const int ro = excl[i] + boff[blockIdx.x];
        row_off[i] = ro;
        cursor[i] = ro;
        nin[i]  = rsqrtf(fmaxf((float)cin[i], 1.f));
        nout[i] = rsqrtf(fmaxf((float)cout_[i], 1.f));
    }
}

__global__ LB256 void k_fill(const int* __restrict__ src, const int* __restrict__ dst,
                             const float* __restrict__ ew, const float* __restrict__ nout,
                             int* __restrict__ cursor, int* __restrict__ sidx,
                             float* __restrict__ wgt, int E) {
    int e = blockIdx.x * 256 + threadIdx.x;
    if (e < E) {
        const int d = dst[e], s = src[e];
        const int pos = atomicAdd(&cursor[d], 1);
        sidx[pos] = s;
        wgt[pos] = nout[s] * ew[e];
    }
}

// C[N][BN] = A[N][K] @ W[K][BN].  BM=64, BK=32, 256 thr as 16x16, 4xTN regs.
template <int BN, int TN>
__global__ LB256 void k_gemm(const float* __restrict__ A, const float* __restrict__ W,
                             float* __restrict__ C, int N, int K) {
    constexpr int BM = 64, BK = 32;
    __shared__ float Xs[BM][BK + 1];
    __shared__ float Ws[BK][BN];

    const int tid = threadIdx.x;
    const int r0 = blockIdx.x * BM;
    const int ty = tid >> 4;
    const int tx = tid & 15;

    float acc[4][TN];
#pragma unroll
    for (int i = 0; i < 4; ++i)
#pragma unroll
        for (int j = 0; j < TN; ++j) acc[i][j] = 0.f;

    const int lrow = tid >> 2;
    const int lc = (tid & 3) * 4;
    const int kr = tid >> 3;

    for (int kc = 0; kc < K; kc += BK) {
        const int gr = r0 + lrow;
        if (gr < N) {
            *(float4*)&Xs[lrow][lc]      = *(const float4*)&A[(size_t)gr * K + kc + lc];
            *(float4*)&Xs[lrow][lc + 16] = *(const float4*)&A[(size_t)gr * K + kc + lc + 16];
        } else {
            *(float4*)&Xs[lrow][lc]      = float4{0.f, 0.f, 0.f, 0.f};
            *(float4*)&Xs[lrow][lc + 16] = float4{0.f, 0.f, 0.f, 0.f};
        }
#pragma unroll
        for (int j = 0; j < BN / 32; ++j) {
            const int c4 = (tid & 7) + j * 8;
            *(float4*)&Ws[kr][c4 * 4] =
                *(const float4*)&W[(size_t)(kc + kr) * BN + c4 * 4];
        }
        __syncthreads();

#pragma unroll
        for (int k = 0; k < BK; ++k) {
            float xv[4];
#pragma unroll
            for (int i = 0; i < 4; ++i) xv[i] = Xs[ty * 4 + i][k];
            float wv[TN];
#pragma unroll
            for (int j4 = 0; j4 < TN / 4; ++j4) {
                const float4 w4 = *(const float4*)&Ws[k][tx * TN + j4 * 4];
                wv[j4 * 4 + 0] = w4.x; wv[j4 * 4 + 1] = w4.y;
                wv[j4 * 4 + 2] = w4.z; wv[j4 * 4 + 3] = w4.w;
            }
#pragma unroll
            for (int i = 0; i < 4; ++i)
#pragma unroll
                for (int j = 0; j < TN; ++j) acc[i][j] = fmaf(xv[i], wv[j], acc[i][j]);
        }
        __syncthreads();
    }

#pragma unroll
    for (int i = 0; i < 4; ++i) {
        const int r = r0 + ty * 4 + i;
        if (r < N) {
#pragma unroll
            for (int j4 = 0; j4 < TN / 4; ++j4) {
                float4 o{acc[i][j4 * 4 + 0], acc[i][j4 * 4 + 1],
                         acc[i][j4 * 4 + 2], acc[i][j4 * 4 + 3]};
                *(float4*)&C[(size_t)r * BN + tx * TN + j4 * 4] = o;
            }
        }
    }
}

// Pull-aggregate: one LANES-lane group per node, float4 per lane.
// out[n] = leaky(nin[n] * sum_j wgt[j] * h[sidx[j]])
template <int F, int LANES>
__global__ LB256 void k_agg(const int* __restrict__ row_off, const int* __restrict__ cnt,
                            const int* __restrict__ sidx, const float* __restrict__ wgt,
                            const float* __restrict__ nin, const float* __restrict__ h,
                            float* __restrict__ out, int N) {
    const int node = blockIdx.x * (256 / LANES) + threadIdx.x / LANES;
    if (node >= N) return;
    const int lane = threadIdx.x % LANES;
    const int start = row_off[node], len = cnt[node];

    float4 acc{0.f, 0.f, 0.f, 0.f};
    int j = 0;
    for (; j + 1 < len; j += 2) {
        const int i0 = start + j, i1 = i0 + 1;
        const int s0 = sidx[i0], s1 = sidx[i1];
        const float c0 = wgt[i0], c1 = wgt[i1];
        const float4 v0 = *(const float4*)&h[(size_t)s0 * F + lane * 4];
        const float4 v1 = *(const float4*)&h[(size_t)s1 * F + lane * 4];
        acc.x = fmaf(c0, v0.x, fmaf(c1, v1.x, acc.x));
        acc.y = fmaf(c0, v0.y, fmaf(c1, v1.y, acc.y));
        acc.z = fmaf(c0, v0.z, fmaf(c1, v1.z, acc.z));
        acc.w = fmaf(c0, v0.w, fmaf(c1, v1.w, acc.w));
    }
    if (j < len) {
        const int i0 = start + j;
        const int s0 = sidx[i0];
        const float c0 = wgt[i0];
        const float4 v0 = *(const float4*)&h[(size_t)s0 * F + lane * 4];
        acc.x = fmaf(c0, v0.x, acc.x);
        acc.y = fmaf(c0, v0.y, acc.y);
        acc.z = fmaf(c0, v0.z, acc.z);
        acc.w = fmaf(c0, v0.w, acc.w);
    }
    const float nd = nin[node];
    float4 o{leaky(acc.x * nd), leaky(acc.y * nd), leaky(acc.z * nd), leaky(acc.w * nd)};
    *(float4*)&out[(size_t)node * F + lane * 4] = o;
}

// Layer-2 aggregate fused with readout: 16 lanes/node, F=64
__global__ LB256 void k_agg_readout(const int* __restrict__ row_off, const int* __restrict__ cnt,
                                    const int* __restrict__ sidx, const float* __restrict__ wgt,
                                    const float* __restrict__ nin, const int* __restrict__ gid,
                                    const float* __restrict__ h, float* __restrict__ gsum,
                                    float* __restrict__ gcnt, int N) {
    const int node = blockIdx.x * 16 + (threadIdx.x >> 4);
    if (node >= N) return;
    const int lane = threadIdx.x & 15;
    const int start = row_off[node], len = cnt[node];

    float4 acc{0.f, 0.f, 0.f, 0.f};
    for (int j = 0; j < len; ++j) {
        const int i0 = start + j;
        const int s0 = sidx[i0];
        const float c0 = wgt[i0];
        const float4 v0 = *(const float4*)&h[(size_t)s0 * 64 + lane * 4];
        acc.x = fmaf(c0, v0.x, acc.x);
        acc.y = fmaf(c0, v0.y, acc.y);
        acc.z = fmaf(c0, v0.z, acc.z);
        acc.w = fmaf(c0, v0.w, acc.w);
    }
    const float nd = nin[node];
    const int g = gid[node];
    float* o = &gsum[(size_t)g * 64 + lane * 4];
    unsafeAtomicAdd(o + 0, leaky(acc.x * nd));
    unsafeAtomicAdd(o + 1, leaky(acc.y * nd));
    unsafeAtomicAdd(o + 2, leaky(acc.z * nd));
    unsafeAtomicAdd(o + 3, leaky(acc.w * nd));
    if (lane == 0) unsafeAtomicAdd(&gcnt[g], 1.f);
}

__global__ LB256 void k_finalize(const float* __restrict__ gsum, const float* __restrict__ gcnt,
                                 float* __restrict__ out, int total) {
    const int i = blockIdx.x * 256 + threadIdx.x;
    if (i < total) out[i] = gsum[i] / fmaxf(gcnt[i >> 6], 1.f);
}

extern "C" void kernel_launch(void* const* d_in, const int* in_sizes, int n_in,
                              void* d_out, int out_size, void* d_ws, size_t ws_size,
                              hipStream_t stream) {
    const float* x   = (const float*)d_in[0];
    const float* ew  = (const float*)d_in[1];
    const float* W1  = (const float*)d_in[2];
    const float* W2  = (const float*)d_in[3];
    const int*   src = (const int*)d_in[4];
    const int*   dst = (const int*)d_in[5];
    const int*   gid = (const int*)d_in[6];

    const int N  = in_sizes[6];      // 50000
    const int E  = in_sizes[4];      // 600000
    const int NG = out_size / 64;    // 128
    const int NB = (N + 255) / 256;  // scan blocks (196)

    const int Na = (N + 63) & ~63;   // 64-elem aligned node arrays

    // ---- workspace layout (4-byte elements, all offsets 256B-aligned) ----
    char* p = (char*)d_ws;
    int*   cin     = (int*)p;                 p += (size_t)Na * 4;   // zeroed
    int*   cout_   = (int*)p;                 p += (size_t)Na * 4;   // zeroed
    float* gsum    = (float*)p;               p += (size_t)NG * 64 * 4; // zeroed
    float* gcnt    = (float*)p;               p += (size_t)((NG + 63) & ~63) * 4; // zeroed
    const size_t zero_bytes = (size_t)(p - (char*)d_ws);
    int*   excl    = (int*)p;                 p += (size_t)Na * 4;
    int*   bsum    = (int*)p;                 p += 256 * 4;
    int*   boff    = (int*)p;                 p += 256 * 4;
    int*   row_off = (int*)p;                 p += (size_t)Na * 4;
    int*   cursor  = (int*)p;                 p += (size_t)Na * 4;
    int*   sidx    = (int*)p;                 p += (size_t)E * 4;
    float* wgt     = (float*)p;               p += (size_t)E * 4;
    float* nin     = (float*)p;               p += (size_t)Na * 4;
    float* nout    = (float*)p;               p += (size_t)Na * 4;
    float* t1      = (float*)p;               p += (size_t)N * 128 * 4;  // also t2
    float* h1      = (float*)p;               /* N*128 floats */

    hipMemsetAsync(d_ws, 0, zero_bytes, stream);

    k_count<<<(E + 255) / 256, 256, 0, stream>>>(src, dst, cin, cout_, E);
    k_scan1<<<NB, 256, 0, stream>>>(cin, excl, bsum, N);
    k_scan2<<<1, 256, 0, stream>>>(bsum, boff, NB);
    k_scan3<<<NB, 256, 0, stream>>>(excl, boff, cin, cout_, row_off, cursor, nin, nout, N);
    k_fill<<<(E + 255) / 256, 256, 0, stream>>>(src, dst, ew, nout, cursor, sidx, wgt, E);

    k_gemm<128, 8><<<(N + 63) / 64, 256, 0, stream>>>(x, W1, t1, N, 128);
    k_agg<128, 32><<<(N + 7) / 8, 256, 0, stream>>>(row_off, cin, sidx, wgt, nin, t1, h1, N);

    k_gemm<64, 4><<<(N + 63) / 64, 256, 0, stream>>>(h1, W2, t1, N, 128);
    k_agg_readout<<<(N + 15) / 16, 256, 0, stream>>>(row_off, cin, sidx, wgt, nin, gid,
                                                     t1, gsum, gcnt, N);

    k_finalize<<<(NG * 64 + 255) / 256, 256, 0, stream>>>(gsum, gcnt, (float*)d_out,
                                                          NG * 64);
}

// Round 6
// 339.088 us; speedup vs baseline: 5.3957x; 1.3235x over previous
//
#include <hip/hip_runtime.h>

// ---------------------------------------------------------------------------
// 2-layer GraphConv (DGL norm='both') + per-graph mean readout.
// R4/R5: R0 showed fp32 global atomics cost ~16B HBM RMW each; R4 counters
// showed k_agg_readout (3.2M atomics -> 8K addrs) = 180us, WRITE 51MB.
// Replace with: k_agg<64,16> -> h2 coalesced, k_rpart (LDS histogram per
// block, no global atomics), k_rfinal (sum partials). Plus 4-wide ILP unroll.
// Pipeline:
//   0. memset: cnt_in, cnt_out
//   1. k_count; 2. k_scan1/2/3; 3. k_fill          (device CSR-by-dst build)
//   4. k_gemm<128>: t1 = x @ W1
//   5. k_agg<128,32>: h1 = leaky(nin * gather-sum(t1))
//   6. k_gemm<64>:  t2 = h1 @ W2
//   7. k_agg<64,16>: h2 = leaky(nin * gather-sum(t2))
//   8. k_rpart:  per-block LDS histogram over graphs -> partials
//   9. k_rfinal: out[g][f] = sum_b part[b][g][f] / count[g]
// ---------------------------------------------------------------------------

#define LB256 __launch_bounds__(256)

constexpr int RB = 128;  // k_rpart blocks; partials = RB * 128 * 64 floats

__device__ __forceinline__ float leaky(float v) { return v > 0.f ? v : 0.01f * v; }

__global__ LB256 void k_count(const int* __restrict__ src, const int* __restrict__ dst,
                              int* __restrict__ cin, int* __restrict__ cout_, int E) {
    int e = blockIdx.x * 256 + threadIdx.x;
    if (e < E) {
        atomicAdd(&cout_[src[e]], 1);
        atomicAdd(&cin[dst[e]], 1);
    }
}

// inclusive block scan helper across 256 threads
__device__ __forceinline__ int block_scan_incl(int v, int t) {
    const int lane = t & 63, w = t >> 6;
#pragma unroll
    for (int off = 1; off < 64; off <<= 1) {
        int n = __shfl_up(v, off);
        if (lane >= off) v += n;
    }
    __shared__ int wsum[4];
    if (lane == 63) wsum[w] = v;
    __syncthreads();
    int base = 0;
#pragma unroll
    for (int k = 0; k < 4; ++k)
        if (k < w) base += wsum[k];
    return v + base;
}

__global__ LB256 void k_scan1(const int* __restrict__ cnt, int* __restrict__ excl,
                              int* __restrict__ bsum, int N) {
    const int t = threadIdx.x, i = blockIdx.x * 256 + t;
    const int orig = (i < N) ? cnt[i] : 0;
    const int incl = block_scan_incl(orig, t);
    if (i < N) excl[i] = incl - orig;
    if (t == 255) bsum[blockIdx.x] = incl;
}

__global__ LB256 void k_scan2(const int* __restrict__ bsum, int* __restrict__ boff, int NB) {
    const int t = threadIdx.x;
    const int orig = (t < NB) ? bsum[t] : 0;
    const int incl = block_scan_incl(orig, t);
    if (t < NB) boff[t] = incl - orig;
}

__global__ LB256 void k_scan3(const int* __restrict__ excl, const int* __restrict__ boff,
                              const int* __restrict__ cin, const int* __restrict__ cout_,
                              int* __restrict__ row_off, int* __restrict__ cursor,
                              float* __restrict__ nin, float* __restrict__ nout, int N) {
    const int i = blockIdx.x * 256 + threadIdx.x;
    if (i < N) {
        const int ro = excl[i] + boff[blockIdx.x];
        row_off[i] = ro;
        cursor[i] = ro;
        nin[i]  = rsqrtf(fmaxf((float)cin[i], 1.f));
        nout[i] = rsqrtf(fmaxf((float)cout_[i], 1.f));
    }
}

__global__ LB256 void k_fill(const int* __restrict__ src, const int* __restrict__ dst,
                             const float* __restrict__ ew, const float* __restrict__ nout,
                             int* __restrict__ cursor, int* __restrict__ sidx,
                             float* __restrict__ wgt, int E) {
    int e = blockIdx.x * 256 + threadIdx.x;
    if (e < E) {
        const int d = dst[e], s = src[e];
        const int pos = atomicAdd(&cursor[d], 1);
        sidx[pos] = s;
        wgt[pos] = nout[s] * ew[e];
    }
}

// C[N][BN] = A[N][K] @ W[K][BN].  BM=64, BK=32, 256 thr as 16x16, 4xTN regs.
template <int BN, int TN>
__global__ LB256 void k_gemm(const float* __restrict__ A, const float* __restrict__ W,
                             float* __restrict__ C, int N, int K) {
    constexpr int BM = 64, BK = 32;
    __shared__ float Xs[BM][BK + 1];
    __shared__ float Ws[BK][BN];

    const int tid = threadIdx.x;
    const int r0 = blockIdx.x * BM;
    const int ty = tid >> 4;
    const int tx = tid & 15;

    float acc[4][TN];
#pragma unroll
    for (int i = 0; i < 4; ++i)
#pragma unroll
        for (int j = 0; j < TN; ++j) acc[i][j] = 0.f;

    const int lrow = tid >> 2;
    const int lc = (tid & 3) * 4;
    const int kr = tid >> 3;

    for (int kc = 0; kc < K; kc += BK) {
        const int gr = r0 + lrow;
        if (gr < N) {
            *(float4*)&Xs[lrow][lc]      = *(const float4*)&A[(size_t)gr * K + kc + lc];
            *(float4*)&Xs[lrow][lc + 16] = *(const float4*)&A[(size_t)gr * K + kc + lc + 16];
        } else {
            *(float4*)&Xs[lrow][lc]      = float4{0.f, 0.f, 0.f, 0.f};
            *(float4*)&Xs[lrow][lc + 16] = float4{0.f, 0.f, 0.f, 0.f};
        }
#pragma unroll
        for (int j = 0; j < BN / 32; ++j) {
            const int c4 = (tid & 7) + j * 8;
            *(float4*)&Ws[kr][c4 * 4] =
                *(const float4*)&W[(size_t)(kc + kr) * BN + c4 * 4];
        }
        __syncthreads();

#pragma unroll
        for (int k = 0; k < BK; ++k) {
            float xv[4];
#pragma unroll
            for (int i = 0; i < 4; ++i) xv[i] = Xs[ty * 4 + i][k];
            float wv[TN];
#pragma unroll
            for (int j4 = 0; j4 < TN / 4; ++j4) {
                const float4 w4 = *(const float4*)&Ws[k][tx * TN + j4 * 4];
                wv[j4 * 4 + 0] = w4.x; wv[j4 * 4 + 1] = w4.y;
                wv[j4 * 4 + 2] = w4.z; wv[j4 * 4 + 3] = w4.w;
            }
#pragma unroll
            for (int i = 0; i < 4; ++i)
#pragma unroll
                for (int j = 0; j < TN; ++j) acc[i][j] = fmaf(xv[i], wv[j], acc[i][j]);
        }
        __syncthreads();
    }

#pragma unroll
    for (int i = 0; i < 4; ++i) {
        const int r = r0 + ty * 4 + i;
        if (r < N) {
#pragma unroll
            for (int j4 = 0; j4 < TN / 4; ++j4) {
                float4 o{acc[i][j4 * 4 + 0], acc[i][j4 * 4 + 1],
                         acc[i][j4 * 4 + 2], acc[i][j4 * 4 + 3]};
                *(float4*)&C[(size_t)r * BN + tx * TN + j4 * 4] = o;
            }
        }
    }
}

// Pull-aggregate: one LANES-lane group per node, float4 per lane, 4-wide ILP.
// out[n] = leaky(nin[n] * sum_j wgt[j] * h[sidx[j]])
template <int F, int LANES>
__global__ LB256 void k_agg(const int* __restrict__ row_off, const int* __restrict__ cnt,
                            const int* __restrict__ sidx, const float* __restrict__ wgt,
                            const float* __restrict__ nin, const float* __restrict__ h,
                            float* __restrict__ out, int N) {
    const int node = blockIdx.x * (256 / LANES) + threadIdx.x / LANES;
    if (node >= N) return;
    const int lane = threadIdx.x % LANES;
    const int start = row_off[node], len = cnt[node];

    float4 accA{0.f, 0.f, 0.f, 0.f}, accB{0.f, 0.f, 0.f, 0.f};
    int j = 0;
    for (; j + 3 < len; j += 4) {
        const int b = start + j;
        const int s0 = sidx[b + 0], s1 = sidx[b + 1], s2 = sidx[b + 2], s3 = sidx[b + 3];
        const float c0 = wgt[b + 0], c1 = wgt[b + 1], c2 = wgt[b + 2], c3 = wgt[b + 3];
        const float4 v0 = *(const float4*)&h[(size_t)s0 * F + lane * 4];
        const float4 v1 = *(const float4*)&h[(size_t)s1 * F + lane * 4];
        const float4 v2 = *(const float4*)&h[(size_t)s2 * F + lane * 4];
        const float4 v3 = *(const float4*)&h[(size_t)s3 * F + lane * 4];
        accA.x = fmaf(c0, v0.x, fmaf(c1, v1.x, accA.x));
        accA.y = fmaf(c0, v0.y, fmaf(c1, v1.y, accA.y));
        accA.z = fmaf(c0, v0.z, fmaf(c1, v1.z, accA.z));
        accA.w = fmaf(c0, v0.w, fmaf(c1, v1.w, accA.w));
        accB.x = fmaf(c2, v2.x, fmaf(c3, v3.x, accB.x));
        accB.y = fmaf(c2, v2.y, fmaf(c3, v3.y, accB.y));
        accB.z = fmaf(c2, v2.z, fmaf(c3, v3.z, accB.z));
        accB.w = fmaf(c2, v2.w, fmaf(c3, v3.w, accB.w));
    }
    for (; j < len; ++j) {
        const int i0 = start + j;
        const int s0 = sidx[i0];
        const float c0 = wgt[i0];
        const float4 v0 = *(const float4*)&h[(size_t)s0 * F + lane * 4];
        accA.x = fmaf(c0, v0.x, accA.x);
        accA.y = fmaf(c0, v0.y, accA.y);
        accA.z = fmaf(c0, v0.z, accA.z);
        accA.w = fmaf(c0, v0.w, accA.w);
    }
    const float nd = nin[node];
    float4 o{leaky((accA.x + accB.x) * nd), leaky((accA.y + accB.y) * nd),
             leaky((accA.z + accB.z) * nd), leaky((accA.w + accB.w) * nd)};
    *(float4*)&out[(size_t)node * F + lane * 4] = o;
}

// Per-block LDS histogram over (graph, feat); coalesced partial dump.
// NG=128 graphs, F=64 feats hardcoded (32KB LDS).
__global__ LB256 void k_rpart(const float* __restrict__ h2, const int* __restrict__ gid,
                              float* __restrict__ part, int* __restrict__ pcnt,
                              int N, int npb) {
    __shared__ float lsum[128 * 64];
    __shared__ int lcnt[128];
    const int t = threadIdx.x;
    for (int i = t; i < 128 * 64; i += 256) lsum[i] = 0.f;
    if (t < 128) lcnt[t] = 0;
    __syncthreads();

    const int n0 = blockIdx.x * npb;
    const int n1 = min(N, n0 + npb);
    const int ty = t >> 6, lane = t & 63;
    for (int n = n0 + ty; n < n1; n += 4) {
        const int g = gid[n];
        atomicAdd(&lsum[g * 64 + lane], h2[(size_t)n * 64 + lane]);
        if (lane == 0) atomicAdd(&lcnt[g], 1);
    }
    __syncthreads();

    float* op = &part[(size_t)blockIdx.x * (128 * 64)];
    for (int i = t; i < 128 * 64; i += 256) op[i] = lsum[i];
    if (t < 128) pcnt[blockIdx.x * 128 + t] = lcnt[t];
}

__global__ LB256 void k_rfinal(const float* __restrict__ part, const int* __restrict__ pcnt,
                               float* __restrict__ out, int total) {
    const int i = blockIdx.x * 256 + threadIdx.x;
    if (i >= total) return;
    const int g = i >> 6;
    float s = 0.f;
    int c = 0;
#pragma unroll 4
    for (int b = 0; b < RB; ++b) {
        s += part[(size_t)b * (128 * 64) + i];
        c += pcnt[b * 128 + g];
    }
    out[i] = s / fmaxf((float)c, 1.f);
}

extern "C" void kernel_launch(void* const* d_in, const int* in_sizes, int n_in,
                              void* d_out, int out_size, void* d_ws, size_t ws_size,
                              hipStream_t stream) {
    const float* x   = (const float*)d_in[0];
    const float* ew  = (const float*)d_in[1];
    const float* W1  = (const float*)d_in[2];
    const float* W2  = (const float*)d_in[3];
    const int*   src = (const int*)d_in[4];
    const int*   dst = (const int*)d_in[5];
    const int*   gid = (const int*)d_in[6];

    const int N  = in_sizes[6];      // 50000
    const int E  = in_sizes[4];      // 600000
    const int NB = (N + 255) / 256;  // scan blocks (196)
    const int Na = (N + 63) & ~63;

    // ---- workspace layout ----
    char* p = (char*)d_ws;
    int*   cin     = (int*)p;                 p += (size_t)Na * 4;   // zeroed
    int*   cout_   = (int*)p;                 p += (size_t)Na * 4;   // zeroed
    const size_t zero_bytes = (size_t)(p - (char*)d_ws);
    int*   excl    = (int*)p;                 p += (size_t)Na * 4;
    int*   bsum    = (int*)p;                 p += 256 * 4;
    int*   boff    = (int*)p;                 p += 256 * 4;
    int*   row_off = (int*)p;                 p += (size_t)Na * 4;
    int*   cursor  = (int*)p;                 p += (size_t)Na * 4;
    int*   sidx    = (int*)p;                 p += (size_t)E * 4;
    float* wgt     = (float*)p;               p += (size_t)E * 4;
    float* nin     = (float*)p;               p += (size_t)Na * 4;
    float* nout    = (float*)p;               p += (size_t)Na * 4;
    float* t1      = (float*)p;               p += (size_t)N * 128 * 4;  // also t2
    float* h1      = (float*)p;               p += (size_t)N * 128 * 4;
    float* h2      = (float*)p;               p += (size_t)N * 64 * 4;
    float* part    = (float*)p;               p += (size_t)RB * 128 * 64 * 4;
    int*   pcnt    = (int*)p;                 /* RB*128 ints */

    hipMemsetAsync(d_ws, 0, zero_bytes, stream);

    k_count<<<(E + 255) / 256, 256, 0, stream>>>(src, dst, cin, cout_, E);
    k_scan1<<<NB, 256, 0, stream>>>(cin, excl, bsum, N);
    k_scan2<<<1, 256, 0, stream>>>(bsum, boff, NB);
    k_scan3<<<NB, 256, 0, stream>>>(excl, boff, cin, cout_, row_off, cursor, nin, nout, N);
    k_fill<<<(E + 255) / 256, 256, 0, stream>>>(src, dst, ew, nout, cursor, sidx, wgt, E);

    k_gemm<128, 8><<<(N + 63) / 64, 256, 0, stream>>>(x, W1, t1, N, 128);
    k_agg<128, 32><<<(N + 7) / 8, 256, 0, stream>>>(row_off, cin, sidx, wgt, nin, t1, h1, N);

    k_gemm<64, 4><<<(N + 63) / 64, 256, 0, stream>>>(h1, W2, t1, N, 128);
    k_agg<64, 16><<<(N + 15) / 16, 256, 0, stream>>>(row_off, cin, sidx, wgt, nin, t1, h2, N);

    const int npb = (N + RB - 1) / RB;
    k_rpart<<<RB, 256, 0, stream>>>(h2, gid, part, pcnt, N, npb);
    k_rfinal<<<(128 * 64 + 255) / 256, 256, 0, stream>>>(part, pcnt, (float*)d_out,
                                                         128 * 64);
}